// Round 1
// baseline (99.981 us; speedup 1.0000x reference)
//
#include <hip/hip_runtime.h>
#include <math.h>

#define N_ROWS 131072
#define N_COLS 1000
#define N_F4   250          // N_COLS / 4
#define NBLK   2048         // 2048 blocks * 4 waves = 8192 waves = 16 rows/wave

__global__ __launch_bounds__(256, 8) void ece_rows(const float* __restrict__ logits,
                                                   const int* __restrict__ labels,
                                                   float* __restrict__ partials) {
    const int lane = threadIdx.x & 63;
    const int wid  = threadIdx.x >> 6;              // wave in block, 0..3
    const int gw   = blockIdx.x * 4 + wid;          // global wave id
    const int totalWaves = gridDim.x * 4;

    float acc_diff = 0.0f;

    for (int r = gw; r < N_ROWS; r += totalWaves) {
        const float4* row = reinterpret_cast<const float4*>(logits + (size_t)r * N_COLS);

        // Load this lane's (up to) 4 float4s; pad missing with large-negative.
        float4 v[4];
        #pragma unroll
        for (int i = 0; i < 4; ++i) {
            const int idx = i * 64 + lane;
            if (idx < N_F4) {
                v[i] = row[idx];
            } else {
                v[i] = make_float4(-1e30f, -1e30f, -1e30f, -1e30f);
            }
        }

        // Local max + first-occurrence column (ascending columns, strict >).
        float m  = -1e30f;
        int   am = N_COLS;
        #pragma unroll
        for (int i = 0; i < 4; ++i) {
            const int c = (i * 64 + lane) * 4;
            if (v[i].x > m) { m = v[i].x; am = c;     }
            if (v[i].y > m) { m = v[i].y; am = c + 1; }
            if (v[i].z > m) { m = v[i].z; am = c + 2; }
            if (v[i].w > m) { m = v[i].w; am = c + 3; }
        }

        // Wave reduce: max value, tie-break to smallest column (jnp.argmax).
        #pragma unroll
        for (int s = 1; s < 64; s <<= 1) {
            const float om = __shfl_xor(m,  s, 64);
            const int   oa = __shfl_xor(am, s, 64);
            if (om > m || (om == m && oa < am)) { m = om; am = oa; }
        }

        // Sum of exp(x - m); padded entries give exp(~-1e30) -> 0.
        float ssum = 0.0f;
        #pragma unroll
        for (int i = 0; i < 4; ++i) {
            ssum += __expf(v[i].x - m);
            ssum += __expf(v[i].y - m);
            ssum += __expf(v[i].z - m);
            ssum += __expf(v[i].w - m);
        }
        #pragma unroll
        for (int s = 1; s < 64; s <<= 1) ssum += __shfl_xor(ssum, s, 64);

        if (lane == 0) {
            const float conf = 1.0f / ssum;              // max softmax
            const float accv = (labels[r] == am) ? 1.0f : 0.0f;
            acc_diff += conf - accv;
        }
    }

    __shared__ float lds[4];
    if (lane == 0) lds[wid] = acc_diff;
    __syncthreads();
    if (threadIdx.x == 0) {
        partials[blockIdx.x] = lds[0] + lds[1] + lds[2] + lds[3];
    }
}

__global__ __launch_bounds__(256) void ece_final(const float* __restrict__ partials,
                                                 float* __restrict__ out) {
    float s = 0.0f;
    for (int i = threadIdx.x; i < NBLK; i += 256) s += partials[i];
    #pragma unroll
    for (int d = 1; d < 64; d <<= 1) s += __shfl_xor(s, d, 64);
    __shared__ float lds[4];
    if ((threadIdx.x & 63) == 0) lds[threadIdx.x >> 6] = s;
    __syncthreads();
    if (threadIdx.x == 0) out[0] = fabsf(lds[0] + lds[1] + lds[2] + lds[3]) / (float)N_ROWS;
}

extern "C" void kernel_launch(void* const* d_in, const int* in_sizes, int n_in,
                              void* d_out, int out_size, void* d_ws, size_t ws_size,
                              hipStream_t stream) {
    const float* logits = (const float*)d_in[0];
    const int*   labels = (const int*)d_in[1];
    float* out      = (float*)d_out;
    float* partials = (float*)d_ws;

    ece_rows<<<NBLK, 256, 0, stream>>>(logits, labels, partials);
    ece_final<<<1, 256, 0, stream>>>(partials, out);
}